// Round 22
// baseline (15314.711 us; speedup 1.0000x reference)
//
#include <hip/hip_runtime.h>
#include <hip/hip_bf16.h>
#include <hip/hip_fp16.h>
#include <math.h>

// Problem sizes
#define BB 256
#define TT 64
#define HH 512
#define SS 256
#define KKC 1024
#define TSLOT (BB*HH)   // 131072

// ws float offsets
#define OFF_XE 0
#define OFF_XS (OFF_XE + TSLOT)
#define OFF_HA (OFF_XS + TSLOT)
#define OFF_HB (OFF_HA + TSLOT)
#define OFF_C  (OFF_HB + TSLOT)
#define OFF_XO (OFF_C  + TSLOT)
#define OFF_SLOT (OFF_XO + TSLOT)            // 1024 u64 = 2048 floats
// transposed weights (always required; 22.6 MB total)
#define OFF_W2T   (OFF_SLOT + 2048)          // [512][512]   W_rb2^T : [k][col]
#define OFF_WEMBT (OFF_W2T + HH*HH)          // [768][512]   W_emb^T : [k][col]
#define OFF_WGT   (OFF_WEMBT + 768*HH)       // [1024][2048] gates: [k][p], p=jl*4+g
#define OFF_WHT   (OFF_WGT + 1024*2048)      // [512][4096]  heads: [k][hd*1024+ko]
#define OFF_TEND  (OFF_WHT + 512*4096)
// batched extension
#define OFF_XEALL (OFF_TEND)                 // [32][B][H]
#define OFF_XSALL (OFF_XEALL + 32*TSLOT)
#define OFF_HALL  (OFF_XSALL + 32*TSLOT)     // [33][B][H]
#define WS_NEED_BATCH (OFF_HALL + 33*TSLOT)
#define WS_NEED_STREAM OFF_TEND

__device__ __forceinline__ unsigned encf(float f) {
  unsigned u = __float_as_uint(f);
  return (u & 0x80000000u) ? ~u : (u | 0x80000000u);
}

__device__ __forceinline__ unsigned long long shfl_xor_u64(unsigned long long v, int m) {
  unsigned lo = (unsigned)v, hi = (unsigned)(v >> 32);
  lo = __shfl_xor(lo, m, 64);
  hi = __shfl_xor(hi, m, 64);
  return ((unsigned long long)hi << 32) | lo;
}

__device__ __forceinline__ int decode_mask(const int* p) {
  if (p == nullptr) return 32;
  unsigned w0 = (unsigned)p[0];
  if (w0 >= 1u && w0 <= 63u) return (int)w0;
  { float f = __uint_as_float(w0);
    if (f >= 1.f && f <= 63.f && f == floorf(f)) return (int)f; }
  if (w0 == 0u) {
    double dv = __hiloint2double(p[1], 0);
    if (dv >= 1.0 && dv <= 63.0 && dv == floor(dv)) return (int)dv;
    return 32;
  }
  if (w0 <= 0xFFFFu) {
    float fb = __uint_as_float(w0 << 16);
    if (fb >= 1.f && fb <= 63.f && fb == floorf(fb)) return (int)fb;
    __half_raw hr; hr.x = (unsigned short)w0;
    float fh = __half2float(__half(hr));
    if (fh >= 1.f && fh <= 63.f && fh == floorf(fh)) return (int)fh;
  }
  return 32;
}

// ---------------- init ----------------
__global__ __launch_bounds__(256) void k_init(
    const float* __restrict__ obs, const float* __restrict__ h0,
    const float* __restrict__ c0, float* __restrict__ ws,
    float* __restrict__ out)
{
  int i = blockIdx.x*256 + threadIdx.x;
  ws[OFF_HA + i] = h0[i];
  ws[OFF_C  + i] = c0[i];
  if (i < BB*4) {
    int b = i >> 2, d = i & 3;
    out[(b*TT + 0)*4 + d]  = obs[(b*TT + 0)*4 + d];
    out[(b*TT + 63)*4 + d] = obs[(b*TT + 63)*4 + d];
  }
}

__global__ __launch_bounds__(256) void k_init_hall(
    const float* __restrict__ h0, float* __restrict__ ws)
{
  int i = blockIdx.x*256 + threadIdx.x;
  ws[OFF_HALL + i] = h0[i];
}

// ---------------- one-time weight transposes (write-coalesced) ----------------
__global__ __launch_bounds__(256) void k_tw(
    const float* __restrict__ W_rb2, const float* __restrict__ W_emb,
    const float* __restrict__ W_ih, const float* __restrict__ W_hh,
    const float* __restrict__ W_fx, const float* __restrict__ W_fy,
    const float* __restrict__ W_fw, const float* __restrict__ W_fh,
    float* __restrict__ ws)
{
  const int N1 = HH*HH, N2 = 768*HH, N3 = 1024*2048, N4 = 512*4096;
  int idx = blockIdx.x*256 + threadIdx.x;   // grid covers N1+N2+N3+N4 exactly
  int i = idx;
  if (i < N1) { int k = i >> 9, col = i & 511; ws[OFF_W2T + i] = W_rb2[col*HH + k]; return; }
  i -= N1;
  if (i < N2) { int k = i >> 9, col = i & 511; ws[OFF_WEMBT + i] = W_emb[col*768 + k]; return; }
  i -= N2;
  if (i < N3) {
    int k = i >> 11, p = i & 2047;
    int jl = p >> 2, g = p & 3;
    int row = g*HH + jl;
    ws[OFF_WGT + i] = (k < HH) ? W_ih[row*HH + k] : W_hh[row*HH + (k - HH)];
    return;
  }
  i -= N3;
  { int k = i >> 12, q = i & 4095;
    int hd = q >> 10, ko = q & 1023;
    const float* Wf = hd==0 ? W_fx : (hd==1 ? W_fy : (hd==2 ? W_fw : W_fh));
    ws[OFF_WHT + i] = Wf[ko*HH + k]; }
}

// ---------------- streaming xe: sample + residual block ----------------
// grid 512 = 32 rowg x 16 colg ; 8 rows x 32 cols/block ; zero k-loop barriers
__global__ __launch_bounds__(256) void k_xe_s(
    const float* __restrict__ obs, const float* __restrict__ cx, const float* __restrict__ cy,
    const float* __restrict__ cw, const float* __restrict__ ch, const int* maskp,
    const float* __restrict__ W_rb1, const float* __restrict__ b_rb1,
    const float* __restrict__ b_rb2,
    const float* __restrict__ W_rbs, const float* __restrict__ b_rbs,
    float* __restrict__ ws, float* __restrict__ xe_out,
    float* __restrict__ out, int t)
{
  int bid = blockIdx.x, tid = threadIdx.x;
  int rowg = bid >> 4, colg = bid & 15;
  int r0 = rowg*8;
  __shared__ float x_sm[8][4];
  __shared__ float xr_smT[HH][8];
  if (tid < 32) {
    int r = tid >> 2, hd = tid & 3, b = r0 + r;
    int mi = decode_mask(maskp);
    float v;
    if (t == 0 || t < mi) {
      v = obs[(b*TT + t)*4 + hd];
    } else {
      const unsigned long long* slots = (const unsigned long long*)(ws + OFF_SLOT);
      unsigned long long s = slots[b*4 + hd];
      unsigned int kidx = 0xFFFFFFFFu - (unsigned int)(s & 0xFFFFFFFFull);
      const float* cen = hd==0 ? cx : (hd==1 ? cy : (hd==2 ? cw : ch));
      v = cen[kidx & (KKC-1)];
    }
    x_sm[r][hd] = v;
    if (t >= 1 && colg == 0) out[(b*TT + t)*4 + hd] = v;
  }
  __syncthreads();
  for (int p = tid; p < 8*HH; p += 256) {
    int r = p & 7, j = p >> 3;
    float4 w = *(const float4*)&W_rb1[j*4];
    float a = b_rb1[j] + x_sm[r][0]*w.x + x_sm[r][1]*w.y + x_sm[r][2]*w.z + x_sm[r][3]*w.w;
    xr_smT[j][r] = fmaxf(a, 0.f);
  }
  __syncthreads();
  int c = tid & 31, rg = tid >> 5;
  int col = colg*32 + c;
  float4 wsd = *(const float4*)&W_rbs[col*4];
  float acc = b_rb2[col] + b_rbs[col]
            + x_sm[rg][0]*wsd.x + x_sm[rg][1]*wsd.y
            + x_sm[rg][2]*wsd.z + x_sm[rg][3]*wsd.w;
  const float* W2T = ws + OFF_W2T;
  #pragma unroll 8
  for (int k = 0; k < HH; k++)
    acc = fmaf(xr_smT[k][rg], W2T[k*HH + col], acc);
  xe_out[(r0+rg)*HH + col] = fmaxf(acc, 0.f);
}

// ---------------- streaming xs ----------------
__global__ __launch_bounds__(256) void k_xs_s(
    const float* __restrict__ social, const float* __restrict__ b_emb,
    const float* __restrict__ ws, const float* __restrict__ XEp,
    float* __restrict__ outp, int t)
{
  int bid = blockIdx.x, tid = threadIdx.x;
  int rowg = bid >> 4, colg = bid & 15;
  int r0 = rowg*8;
  int c = tid & 31, rg = tid >> 5;
  int col = colg*32 + c;
  float acc = b_emb[col];
  const float* WT = ws + OFF_WEMBT;
  const float* arow = &XEp[(r0+rg)*HH];
  #pragma unroll 4
  for (int k = 0; k < HH; k += 4) {
    float4 a = *(const float4*)&arow[k];
    acc = fmaf(a.x, WT[(k+0)*HH + col], acc);
    acc = fmaf(a.y, WT[(k+1)*HH + col], acc);
    acc = fmaf(a.z, WT[(k+2)*HH + col], acc);
    acc = fmaf(a.w, WT[(k+3)*HH + col], acc);
  }
  const float* srow = &social[((size_t)(r0+rg)*TT + t)*SS];
  #pragma unroll 4
  for (int k = 0; k < SS; k += 4) {
    float4 a = *(const float4*)&srow[k];
    acc = fmaf(a.x, WT[(HH+k+0)*HH + col], acc);
    acc = fmaf(a.y, WT[(HH+k+1)*HH + col], acc);
    acc = fmaf(a.z, WT[(HH+k+2)*HH + col], acc);
    acc = fmaf(a.w, WT[(HH+k+3)*HH + col], acc);
  }
  outp[(r0+rg)*HH + col] = fmaxf(acc, 0.f);
}

// ---------------- streaming gates + cell update ----------------
// grid 512 = 16 rowg x 32 colg ; 16 rows x 64 gate-cols ; zero k-loop barriers
__global__ __launch_bounds__(256) void k_gates_s(
    const float* __restrict__ b_ih, const float* __restrict__ b_hh,
    const float* __restrict__ XSp, const float* __restrict__ XEp,
    float* __restrict__ ws, const float* __restrict__ h_cur,
    float* __restrict__ h_nxt)
{
  int bid = blockIdx.x, tid = threadIdx.x;
  int rowg = bid >> 5, colg = bid & 31;
  int r0 = rowg*16;
  int tx = tid & 63, ty = tid >> 6;
  __shared__ float gt[16][66];
  int wrow = (tx & 3)*HH + colg*16 + (tx >> 2);
  int pcol = colg*64 + tx;
  float bias = b_ih[wrow] + b_hh[wrow];
  float acc[4];
  #pragma unroll
  for (int i = 0; i < 4; i++) acc[i] = bias;
  const float* WgT = ws + OFF_WGT;
  const float* a0p = &XSp[(r0+ty*4+0)*HH];
  const float* a1p = &XSp[(r0+ty*4+1)*HH];
  const float* a2p = &XSp[(r0+ty*4+2)*HH];
  const float* a3p = &XSp[(r0+ty*4+3)*HH];
  #pragma unroll 4
  for (int k = 0; k < HH; k += 4) {
    float4 a0 = *(const float4*)&a0p[k];
    float4 a1 = *(const float4*)&a1p[k];
    float4 a2 = *(const float4*)&a2p[k];
    float4 a3 = *(const float4*)&a3p[k];
    float w0 = WgT[(k+0)*2048 + pcol];
    float w1 = WgT[(k+1)*2048 + pcol];
    float w2 = WgT[(k+2)*2048 + pcol];
    float w3 = WgT[(k+3)*2048 + pcol];
    acc[0] = fmaf(a0.x, w0, acc[0]); acc[1] = fmaf(a1.x, w0, acc[1]);
    acc[2] = fmaf(a2.x, w0, acc[2]); acc[3] = fmaf(a3.x, w0, acc[3]);
    acc[0] = fmaf(a0.y, w1, acc[0]); acc[1] = fmaf(a1.y, w1, acc[1]);
    acc[2] = fmaf(a2.y, w1, acc[2]); acc[3] = fmaf(a3.y, w1, acc[3]);
    acc[0] = fmaf(a0.z, w2, acc[0]); acc[1] = fmaf(a1.z, w2, acc[1]);
    acc[2] = fmaf(a2.z, w2, acc[2]); acc[3] = fmaf(a3.z, w2, acc[3]);
    acc[0] = fmaf(a0.w, w3, acc[0]); acc[1] = fmaf(a1.w, w3, acc[1]);
    acc[2] = fmaf(a2.w, w3, acc[2]); acc[3] = fmaf(a3.w, w3, acc[3]);
  }
  const float* h0p = &h_cur[(r0+ty*4+0)*HH];
  const float* h1p = &h_cur[(r0+ty*4+1)*HH];
  const float* h2p = &h_cur[(r0+ty*4+2)*HH];
  const float* h3p = &h_cur[(r0+ty*4+3)*HH];
  #pragma unroll 4
  for (int k = 0; k < HH; k += 4) {
    float4 a0 = *(const float4*)&h0p[k];
    float4 a1 = *(const float4*)&h1p[k];
    float4 a2 = *(const float4*)&h2p[k];
    float4 a3 = *(const float4*)&h3p[k];
    float w0 = WgT[(HH+k+0)*2048 + pcol];
    float w1 = WgT[(HH+k+1)*2048 + pcol];
    float w2 = WgT[(HH+k+2)*2048 + pcol];
    float w3 = WgT[(HH+k+3)*2048 + pcol];
    acc[0] = fmaf(a0.x, w0, acc[0]); acc[1] = fmaf(a1.x, w0, acc[1]);
    acc[2] = fmaf(a2.x, w0, acc[2]); acc[3] = fmaf(a3.x, w0, acc[3]);
    acc[0] = fmaf(a0.y, w1, acc[0]); acc[1] = fmaf(a1.y, w1, acc[1]);
    acc[2] = fmaf(a2.y, w1, acc[2]); acc[3] = fmaf(a3.y, w1, acc[3]);
    acc[0] = fmaf(a0.z, w2, acc[0]); acc[1] = fmaf(a1.z, w2, acc[1]);
    acc[2] = fmaf(a2.z, w2, acc[2]); acc[3] = fmaf(a3.z, w2, acc[3]);
    acc[0] = fmaf(a0.w, w3, acc[0]); acc[1] = fmaf(a1.w, w3, acc[1]);
    acc[2] = fmaf(a2.w, w3, acc[2]); acc[3] = fmaf(a3.w, w3, acc[3]);
  }
  #pragma unroll
  for (int i = 0; i < 4; i++) gt[ty*4 + i][tx] = acc[i];
  __syncthreads();
  float* C = ws + OFF_C;
  float* XO = ws + OFF_XO;
  {
    int r = tid >> 4, jl = tid & 15;
    float4 g4 = *(const float4*)&gt[r][jl*4];   // i,f,g,o
    int b = r0 + r, jglob = colg*16 + jl;
    float co = C[b*HH + jglob];
    double si = 1.0/(1.0 + exp(-(double)g4.x));
    double sf = 1.0/(1.0 + exp(-(double)g4.y));
    double tg = tanh((double)g4.z);
    double so = 1.0/(1.0 + exp(-(double)g4.w));
    float c2 = (float)(sf*(double)co + si*tg);
    float h2 = (float)(so*tanh((double)c2));
    C[b*HH + jglob] = c2;
    h_nxt[b*HH + jglob] = h2;
    XO[b*HH + jglob] = h2 + XEp[b*HH + jglob];
  }
  if (bid == 0) {
    unsigned long long* slots = (unsigned long long*)(ws + OFF_SLOT);
    for (int p = tid; p < BB*4; p += 256) slots[p] = 0ull;
  }
}

// ---------------- streaming heads + argmax ----------------
// grid 1024 = 16 rowg x 64 colg ; 16 rows x 64 head-cols ; zero k-loop barriers
__global__ __launch_bounds__(256) void k_heads_s(
    const float* __restrict__ b_fx, const float* __restrict__ b_fy,
    const float* __restrict__ b_fw, const float* __restrict__ b_fh,
    const int* maskp, float* __restrict__ ws, float* __restrict__ out, int t)
{
  int bid = blockIdx.x, tid = threadIdx.x;
  int rowg = bid >> 6, colg = bid & 63;
  int r0 = rowg*16;
  int hd = colg >> 4;
  int kbase = (colg & 15)*64;
  int tx = tid & 63, ty = tid >> 6;
  const float* bf = hd==0 ? b_fx : (hd==1 ? b_fy : (hd==2 ? b_fw : b_fh));
  const float* XO = ws + OFF_XO;
  int ko = kbase + tx;
  int q = hd*1024 + ko;
  float acc[4];
  float binit = bf[ko];
  #pragma unroll
  for (int i = 0; i < 4; i++) acc[i] = binit;
  const float* WhT = ws + OFF_WHT;
  const float* a0p = &XO[(r0+ty*4+0)*HH];
  const float* a1p = &XO[(r0+ty*4+1)*HH];
  const float* a2p = &XO[(r0+ty*4+2)*HH];
  const float* a3p = &XO[(r0+ty*4+3)*HH];
  #pragma unroll 4
  for (int k = 0; k < HH; k += 4) {
    float4 a0 = *(const float4*)&a0p[k];
    float4 a1 = *(const float4*)&a1p[k];
    float4 a2 = *(const float4*)&a2p[k];
    float4 a3 = *(const float4*)&a3p[k];
    float w0 = WhT[(k+0)*4096 + q];
    float w1 = WhT[(k+1)*4096 + q];
    float w2 = WhT[(k+2)*4096 + q];
    float w3 = WhT[(k+3)*4096 + q];
    acc[0] = fmaf(a0.x, w0, acc[0]); acc[1] = fmaf(a1.x, w0, acc[1]);
    acc[2] = fmaf(a2.x, w0, acc[2]); acc[3] = fmaf(a3.x, w0, acc[3]);
    acc[0] = fmaf(a0.y, w1, acc[0]); acc[1] = fmaf(a1.y, w1, acc[1]);
    acc[2] = fmaf(a2.y, w1, acc[2]); acc[3] = fmaf(a3.y, w1, acc[3]);
    acc[0] = fmaf(a0.z, w2, acc[0]); acc[1] = fmaf(a1.z, w2, acc[1]);
    acc[2] = fmaf(a2.z, w2, acc[2]); acc[3] = fmaf(a3.z, w2, acc[3]);
    acc[0] = fmaf(a0.w, w3, acc[0]); acc[1] = fmaf(a1.w, w3, acc[1]);
    acc[2] = fmaf(a2.w, w3, acc[2]); acc[3] = fmaf(a3.w, w3, acc[3]);
  }
  float* obase = out + (size_t)BB*TT*4 + (size_t)hd*BB*63*KKC;
  unsigned long long* slots = (unsigned long long*)(ws + OFF_SLOT);
  bool do_argmax = (t + 1 >= decode_mask(maskp)) && (t < 62);
  #pragma unroll
  for (int i = 0; i < 4; i++) {
    int b = r0 + ty*4 + i;
    obase[(size_t)b*63*KKC + (size_t)t*KKC + ko] = acc[i];
    if (do_argmax) {
      unsigned long long cd = ((unsigned long long)encf(acc[i]) << 32)
                            | (unsigned long long)(0xFFFFFFFFu - (unsigned)ko);
      #pragma unroll
      for (int m = 1; m < 64; m <<= 1) {
        unsigned long long o = shfl_xor_u64(cd, m);
        cd = (o > cd) ? o : cd;
      }
      if (tx == 0) atomicMax(&slots[b*4 + hd], cd);
    }
  }
}

// ---------------- batched teacher xe: grid (512, 32) (r21 verbatim) ----------------
__global__ __launch_bounds__(256) void k_xe_batch(
    const float* __restrict__ obs,
    const float* __restrict__ W_rb1, const float* __restrict__ b_rb1,
    const float* __restrict__ W_rb2, const float* __restrict__ b_rb2,
    const float* __restrict__ W_rbs, const float* __restrict__ b_rbs,
    float* __restrict__ ws, float* __restrict__ out)
{
  int bid = blockIdx.x, tid = threadIdx.x, t = blockIdx.y;
  int rowg = bid >> 4, colg = bid & 15;
  int r0 = rowg*8, c0 = colg*32;
  __shared__ float x_sm[8][4];
  __shared__ float xr_smT[HH][8];
  __shared__ float w_sm[2][64][36];
  int swc[2], skq[2];
  #pragma unroll
  for (int p = 0; p < 2; p++) { int idx = tid + p*256; swc[p] = idx >> 4; skq[p] = idx & 15; }
  float4 wReg[2];
  #pragma unroll
  for (int p = 0; p < 2; p++)
    wReg[p] = *(const float4*)&W_rb2[(c0+swc[p])*HH + 0 + skq[p]*4];

  if (tid < 32) {
    int r = tid >> 2, hd = tid & 3, b = r0 + r;
    float v = obs[(b*TT + t)*4 + hd];
    x_sm[r][hd] = v;
    if (t >= 1 && colg == 0) out[(b*TT + t)*4 + hd] = v;
  }
  __syncthreads();
  for (int p = tid; p < 8*HH; p += 256) {
    int r = p & 7, j = p >> 3;
    float4 w = *(const float4*)&W_rb1[j*4];
    float a = b_rb1[j] + x_sm[r][0]*w.x + x_sm[r][1]*w.y + x_sm[r][2]*w.z + x_sm[r][3]*w.w;
    xr_smT[j][r] = fmaxf(a, 0.f);
  }
  int c = tid & 31, rg = tid >> 5;
  int col = c0 + c;
  float4 wsd = *(const float4*)&W_rbs[col*4];
  float acc = b_rb2[col] + b_rbs[col]
            + x_sm[rg][0]*wsd.x + x_sm[rg][1]*wsd.y
            + x_sm[rg][2]*wsd.z + x_sm[rg][3]*wsd.w;
  #pragma unroll
  for (int p = 0; p < 2; p++) {
    w_sm[0][skq[p]*4+0][swc[p]] = wReg[p].x; w_sm[0][skq[p]*4+1][swc[p]] = wReg[p].y;
    w_sm[0][skq[p]*4+2][swc[p]] = wReg[p].z; w_sm[0][skq[p]*4+3][swc[p]] = wReg[p].w;
  }
  __syncthreads();
  for (int kt = 0; kt < 8; kt++) {
    int buf = kt & 1;
    if (kt < 7) {
      int k0n = (kt+1)*64;
      #pragma unroll
      for (int p = 0; p < 2; p++)
        wReg[p] = *(const float4*)&W_rb2[(c0+swc[p])*HH + k0n + skq[p]*4];
    }
    #pragma unroll 8
    for (int kk = 0; kk < 64; kk++)
      acc = fmaf(xr_smT[kt*64+kk][rg], w_sm[buf][kk][c], acc);
    if (kt < 7) {
      __syncthreads();
      int nb = buf ^ 1;
      #pragma unroll
      for (int p = 0; p < 2; p++) {
        w_sm[nb][skq[p]*4+0][swc[p]] = wReg[p].x; w_sm[nb][skq[p]*4+1][swc[p]] = wReg[p].y;
        w_sm[nb][skq[p]*4+2][swc[p]] = wReg[p].z; w_sm[nb][skq[p]*4+3][swc[p]] = wReg[p].w;
      }
      __syncthreads();
    }
  }
  ws[OFF_XEALL + (size_t)t*TSLOT + (r0+rg)*HH + col] = fmaxf(acc, 0.f);
}

// ---------------- batched teacher xs via streaming: grid (512, 32) ----------------
__global__ __launch_bounds__(256) void k_xs_batch(
    const float* __restrict__ social, const float* __restrict__ b_emb,
    float* __restrict__ ws)
{
  int bid = blockIdx.x, tid = threadIdx.x, t = blockIdx.y;
  int rowg = bid >> 4, colg = bid & 15;
  int r0 = rowg*8;
  const float* XEp = ws + OFF_XEALL + (size_t)t*TSLOT;
  float* outp = ws + OFF_XSALL + (size_t)t*TSLOT;
  int c = tid & 31, rg = tid >> 5;
  int col = colg*32 + c;
  float acc = b_emb[col];
  const float* WT = ws + OFF_WEMBT;
  const float* arow = &XEp[(r0+rg)*HH];
  #pragma unroll 4
  for (int k = 0; k < HH; k += 4) {
    float4 a = *(const float4*)&arow[k];
    acc = fmaf(a.x, WT[(k+0)*HH + col], acc);
    acc = fmaf(a.y, WT[(k+1)*HH + col], acc);
    acc = fmaf(a.z, WT[(k+2)*HH + col], acc);
    acc = fmaf(a.w, WT[(k+3)*HH + col], acc);
  }
  const float* srow = &social[((size_t)(r0+rg)*TT + t)*SS];
  #pragma unroll 4
  for (int k = 0; k < SS; k += 4) {
    float4 a = *(const float4*)&srow[k];
    acc = fmaf(a.x, WT[(HH+k+0)*HH + col], acc);
    acc = fmaf(a.y, WT[(HH+k+1)*HH + col], acc);
    acc = fmaf(a.z, WT[(HH+k+2)*HH + col], acc);
    acc = fmaf(a.w, WT[(HH+k+3)*HH + col], acc);
  }
  outp[(r0+rg)*HH + col] = fmaxf(acc, 0.f);
}

// ---------------- deferred teacher heads: streaming, grid (1024, 31) ----------------
__global__ __launch_bounds__(256) void k_heads_def(
    const float* __restrict__ b_fx, const float* __restrict__ b_fy,
    const float* __restrict__ b_fw, const float* __restrict__ b_fh,
    const float* __restrict__ ws, float* __restrict__ out)
{
  int bid = blockIdx.x, tid = threadIdx.x, t = blockIdx.y;
  int rowg = bid >> 6, colg = bid & 63;
  int r0 = rowg*16;
  int hd = colg >> 4;
  int kbase = (colg & 15)*64;
  int tx = tid & 63, ty = tid >> 6;
  const float* bf = hd==0 ? b_fx : (hd==1 ? b_fy : (hd==2 ? b_fw : b_fh));
  const float* Hn  = ws + OFF_HALL  + (size_t)(t+1)*TSLOT;
  const float* XEt = ws + OFF_XEALL + (size_t)t*TSLOT;
  int ko = kbase + tx;
  int q = hd*1024 + ko;
  float acc[4];
  float binit = bf[ko];
  #pragma unroll
  for (int i = 0; i < 4; i++) acc[i] = binit;
  const float* WhT = ws + OFF_WHT;
  const float* h0p = &Hn[(r0+ty*4+0)*HH];  const float* e0p = &XEt[(r0+ty*4+0)*HH];
  const float* h1p = &Hn[(r0+ty*4+1)*HH];  const float* e1p = &XEt[(r0+ty*4+1)*HH];
  const float* h2p = &Hn[(r0+ty*4+2)*HH];  const float* e2p = &XEt[(r0+ty*4+2)*HH];
  const float* h3p = &Hn[(r0+ty*4+3)*HH];  const float* e3p = &XEt[(r0+ty*4+3)*HH];
  #pragma unroll 4
  for (int k = 0; k < HH; k += 4) {
    float4 x0 = *(const float4*)&h0p[k]; float4 y0 = *(const float4*)&e0p[k];
    float4 x1 = *(const float4*)&h1p[k]; float4 y1 = *(const float4*)&e1p[k];
    float4 x2 = *(const float4*)&h2p[k]; float4 y2 = *(const float4*)&e2p[k];
    float4 x3 = *(const float4*)&h3p[k]; float4 y3 = *(const float4*)&e3p[k];
    float4 a0 = make_float4(x0.x+y0.x, x0.y+y0.y, x0.z+y0.z, x0.w+y0.w);
    float4 a1 = make_float4(x1.x+y1.x, x1.y+y1.y, x1.z+y1.z, x1.w+y1.w);
    float4 a2 = make_float4(x2.x+y2.x, x2.y+y2.y, x2.z+y2.z, x2.w+y2.w);
    float4 a3 = make_float4(x3.x+y3.x, x3.y+y3.y, x3.z+y3.z, x3.w+y3.w);
    float w0 = WhT[(k+0)*4096 + q];
    float w1 = WhT[(k+1)*4096 + q];
    float w2 = WhT[(k+2)*4096 + q];
    float w3 = WhT[(k+3)*4096 + q];
    acc[0] = fmaf(a0.x, w0, acc[0]); acc[1] = fmaf(a1.x, w0, acc[1]);
    acc[2] = fmaf(a2.x, w0, acc[2]); acc[3] = fmaf(a3.x, w0, acc[3]);
    acc[0] = fmaf(a0.y, w1, acc[0]); acc[1] = fmaf(a1.y, w1, acc[1]);
    acc[2] = fmaf(a2.y, w1, acc[2]); acc[3] = fmaf(a3.y, w1, acc[3]);
    acc[0] = fmaf(a0.z, w2, acc[0]); acc[1] = fmaf(a1.z, w2, acc[1]);
    acc[2] = fmaf(a2.z, w2, acc[2]); acc[3] = fmaf(a3.z, w2, acc[3]);
    acc[0] = fmaf(a0.w, w3, acc[0]); acc[1] = fmaf(a1.w, w3, acc[1]);
    acc[2] = fmaf(a2.w, w3, acc[2]); acc[3] = fmaf(a3.w, w3, acc[3]);
  }
  float* obase = out + (size_t)BB*TT*4 + (size_t)hd*BB*63*KKC;
  #pragma unroll
  for (int i = 0; i < 4; i++) {
    int b = r0 + ty*4 + i;
    obase[(size_t)b*63*KKC + (size_t)t*KKC + ko] = acc[i];
  }
}

extern "C" void kernel_launch(void* const* d_in, const int* in_sizes, int n_in,
                              void* d_out, int out_size, void* d_ws, size_t ws_size,
                              hipStream_t stream)
{
  const float* obs    = (const float*)d_in[0];
  const float* social = (const float*)d_in[1];
  const int*   maskp  = (const int*)d_in[2];
  const float* cx = (const float*)d_in[3];
  const float* cy = (const float*)d_in[4];
  const float* cw = (const float*)d_in[5];
  const float* ch = (const float*)d_in[6];
  const float* W_rb1 = (const float*)d_in[7];
  const float* b_rb1 = (const float*)d_in[8];
  const float* W_rb2 = (const float*)d_in[9];
  const float* b_rb2 = (const float*)d_in[10];
  const float* W_rbs = (const float*)d_in[11];
  const float* b_rbs = (const float*)d_in[12];
  const float* W_emb = (const float*)d_in[13];
  const float* b_emb = (const float*)d_in[14];
  const float* W_ih  = (const float*)d_in[15];
  const float* b_ih  = (const float*)d_in[16];
  const float* W_hh  = (const float*)d_in[17];
  const float* b_hh  = (const float*)d_in[18];
  const float* W_fx  = (const float*)d_in[19];
  const float* b_fx  = (const float*)d_in[20];
  const float* W_fy  = (const float*)d_in[21];
  const float* b_fy  = (const float*)d_in[22];
  const float* W_fw  = (const float*)d_in[23];
  const float* b_fw  = (const float*)d_in[24];
  const float* W_fh  = (const float*)d_in[25];
  const float* b_fh  = (const float*)d_in[26];
  const float* h0 = (const float*)d_in[27];
  const float* c0 = (const float*)d_in[28];
  float* ws = (float*)d_ws;
  float* out = (float*)d_out;

  const bool batched = ws_size >= (size_t)WS_NEED_BATCH * sizeof(float);

  hipLaunchKernelGGL(k_init, dim3(512), dim3(256), 0, stream, obs, h0, c0, ws, out);
  // one-time transposes: (N1+N2+N3+N4)/256 = 18944 blocks exactly
  hipLaunchKernelGGL(k_tw, dim3(18944), dim3(256), 0, stream,
                     W_rb2, W_emb, W_ih, W_hh, W_fx, W_fy, W_fw, W_fh, ws);

  if (batched) {
    hipLaunchKernelGGL(k_init_hall, dim3(512), dim3(256), 0, stream, h0, ws);
    hipLaunchKernelGGL(k_xe_batch, dim3(512, 32), dim3(256), 0, stream,
                       obs, W_rb1, b_rb1, W_rb2, b_rb2, W_rbs, b_rbs, ws, out);
    hipLaunchKernelGGL(k_xs_batch, dim3(512, 32), dim3(256), 0, stream,
                       social, b_emb, ws);
    for (int t = 0; t < 32; t++) {
      const float* XSp = ws + OFF_XSALL + (size_t)t*TSLOT;
      const float* XEp = ws + OFF_XEALL + (size_t)t*TSLOT;
      const float* hc  = ws + OFF_HALL + (size_t)t*TSLOT;
      float*       hn  = ws + OFF_HALL + (size_t)(t+1)*TSLOT;
      hipLaunchKernelGGL(k_gates_s, dim3(512), dim3(256), 0, stream,
                         b_ih, b_hh, XSp, XEp, ws, hc, hn);
    }
    hipLaunchKernelGGL(k_heads_s, dim3(1024), dim3(256), 0, stream,
                       b_fx, b_fy, b_fw, b_fh, maskp, ws, out, 31);
    for (int t = 32; t < 63; t++) {
      const float* hc = (t == 32) ? ws + OFF_HALL + (size_t)32*TSLOT
                                  : ((t & 1) ? ws + OFF_HB : ws + OFF_HA);
      float*       hn = (t & 1) ? ws + OFF_HA : ws + OFF_HB;
      if (t == 32) hn = ws + OFF_HB;
      hipLaunchKernelGGL(k_xe_s, dim3(512), dim3(256), 0, stream,
                         obs, cx, cy, cw, ch, maskp,
                         W_rb1, b_rb1, b_rb2, W_rbs, b_rbs,
                         ws, ws + OFF_XE, out, t);
      hipLaunchKernelGGL(k_xs_s, dim3(512), dim3(256), 0, stream,
                         social, b_emb, ws, ws + OFF_XE, ws + OFF_XS, t);
      hipLaunchKernelGGL(k_gates_s, dim3(512), dim3(256), 0, stream,
                         b_ih, b_hh, ws + OFF_XS, ws + OFF_XE, ws, hc, hn);
      hipLaunchKernelGGL(k_heads_s, dim3(1024), dim3(256), 0, stream,
                         b_fx, b_fy, b_fw, b_fh, maskp, ws, out, t);
    }
    hipLaunchKernelGGL(k_heads_def, dim3(1024, 31), dim3(256), 0, stream,
                       b_fx, b_fy, b_fw, b_fh, ws, out);
  } else {
    for (int t = 0; t < 63; t++) {
      const float* hc = (t & 1) ? ws + OFF_HB : ws + OFF_HA;
      float*       hn = (t & 1) ? ws + OFF_HA : ws + OFF_HB;
      hipLaunchKernelGGL(k_xe_s, dim3(512), dim3(256), 0, stream,
                         obs, cx, cy, cw, ch, maskp,
                         W_rb1, b_rb1, b_rb2, W_rbs, b_rbs,
                         ws, ws + OFF_XE, out, t);
      hipLaunchKernelGGL(k_xs_s, dim3(512), dim3(256), 0, stream,
                         social, b_emb, ws, ws + OFF_XE, ws + OFF_XS, t);
      hipLaunchKernelGGL(k_gates_s, dim3(512), dim3(256), 0, stream,
                         b_ih, b_hh, ws + OFF_XS, ws + OFF_XE, ws, hc, hn);
      hipLaunchKernelGGL(k_heads_s, dim3(1024), dim3(256), 0, stream,
                         b_fx, b_fy, b_fw, b_fh, maskp, ws, out, t);
    }
  }
}

// Round 23
// 6196.281 us; speedup vs baseline: 2.4716x; 2.4716x over previous
//
#include <hip/hip_runtime.h>
#include <hip/hip_bf16.h>
#include <hip/hip_fp16.h>
#include <math.h>

// Problem sizes
#define BB 256
#define TT 64
#define HH 512
#define SS 256
#define KKC 1024
#define TSLOT (BB*HH)   // floats per timestep slot (131072)

// ws float offsets — base region 790,528 floats (3.16 MB)
#define OFF_XE 0
#define OFF_XS (OFF_XE + BB*HH)
#define OFF_HA (OFF_XS + BB*HH)
#define OFF_HB (OFF_HA + BB*HH)
#define OFF_C  (OFF_HB + BB*HH)
#define OFF_XO (OFF_C  + BB*HH)
#define OFF_SLOT (OFF_XO + BB*HH)          // 1024 u64 argmax slots = 2048 floats
// batched-path extension (used only when ws_size is large enough)
#define OFF_XEALL (OFF_SLOT + 2048)        // [32][B][H]
#define OFF_XSALL (OFF_XEALL + 32*TSLOT)   // [32][B][H]
#define OFF_HALL  (OFF_XSALL + 32*TSLOT)   // [33][B][H]
#define WS_NEED_FLOATS (OFF_HALL + 33*TSLOT)

__device__ __forceinline__ unsigned encf(float f) {
  unsigned u = __float_as_uint(f);
  return (u & 0x80000000u) ? ~u : (u | 0x80000000u);
}

__device__ __forceinline__ unsigned long long shfl_xor_u64(unsigned long long v, int m) {
  unsigned lo = (unsigned)v, hi = (unsigned)(v >> 32);
  lo = __shfl_xor(lo, m, 64);
  hi = __shfl_xor(hi, m, 64);
  return ((unsigned long long)hi << 32) | lo;
}

// mask decode (robust; proven on this dataset in round 11)
__device__ __forceinline__ int decode_mask(const int* p) {
  if (p == nullptr) return 32;
  unsigned w0 = (unsigned)p[0];
  if (w0 >= 1u && w0 <= 63u) return (int)w0;
  { float f = __uint_as_float(w0);
    if (f >= 1.f && f <= 63.f && f == floorf(f)) return (int)f; }
  if (w0 == 0u) {
    double dv = __hiloint2double(p[1], 0);
    if (dv >= 1.0 && dv <= 63.0 && dv == floor(dv)) return (int)dv;
    return 32;
  }
  if (w0 <= 0xFFFFu) {
    float fb = __uint_as_float(w0 << 16);
    if (fb >= 1.f && fb <= 63.f && fb == floorf(fb)) return (int)fb;
    __half_raw hr; hr.x = (unsigned short)w0;
    float fh = __half2float(__half(hr));
    if (fh >= 1.f && fh <= 63.f && fh == floorf(fh)) return (int)fh;
  }
  return 32;
}

// ---------------- init: h,c and output edges ----------------
__global__ __launch_bounds__(256) void k_init(
    const float* __restrict__ obs, const float* __restrict__ h0,
    const float* __restrict__ c0, float* __restrict__ ws,
    float* __restrict__ out)
{
  int i = blockIdx.x*256 + threadIdx.x;   // 512 blocks -> BB*HH
  ws[OFF_HA + i] = h0[i];
  ws[OFF_C  + i] = c0[i];
  if (i < BB*4) {
    int b = i >> 2, d = i & 3;
    out[(b*TT + 0)*4 + d]  = obs[(b*TT + 0)*4 + d];
    out[(b*TT + 63)*4 + d] = obs[(b*TT + 63)*4 + d];
  }
}

// batched path: h0 -> HALL[0]
__global__ __launch_bounds__(256) void k_init_hall(
    const float* __restrict__ h0, float* __restrict__ ws)
{
  int i = blockIdx.x*256 + threadIdx.x;
  ws[OFF_HALL + i] = h0[i];
}

// ---------------- AR phase 1: sample + residual block -> OFF_XE ----------------
// grid 512 = 32 rowg x 16 colg ; tile 8 rows x 32 cols, k=512 ; W double-buffered
__global__ __launch_bounds__(256) void k_xe(
    const float* __restrict__ obs, const float* __restrict__ cx, const float* __restrict__ cy,
    const float* __restrict__ cw, const float* __restrict__ ch, const int* maskp,
    const float* __restrict__ W_rb1, const float* __restrict__ b_rb1,
    const float* __restrict__ W_rb2, const float* __restrict__ b_rb2,
    const float* __restrict__ W_rbs, const float* __restrict__ b_rbs,
    float* __restrict__ ws, float* __restrict__ out, int t)
{
  int bid = blockIdx.x, tid = threadIdx.x;
  int rowg = bid >> 4, colg = bid & 15;
  int r0 = rowg*8, c0 = colg*32;
  __shared__ float x_sm[8][4];
  __shared__ float xr_smT[HH][8];
  __shared__ float w_sm[2][64][36];
  int swc[2], skq[2];
  #pragma unroll
  for (int p = 0; p < 2; p++) { int idx = tid + p*256; swc[p] = idx >> 4; skq[p] = idx & 15; }
  float4 wReg[2];
  #pragma unroll
  for (int p = 0; p < 2; p++)
    wReg[p] = *(const float4*)&W_rb2[(c0+swc[p])*HH + 0 + skq[p]*4];

  if (tid < 32) {
    int r = tid >> 2, hd = tid & 3, b = r0 + r;
    int mi = decode_mask(maskp);
    float v;
    if (t == 0 || t < mi) {
      v = obs[(b*TT + t)*4 + hd];
    } else {
      const unsigned long long* slots = (const unsigned long long*)(ws + OFF_SLOT);
      unsigned long long s = slots[b*4 + hd];
      unsigned int kidx = 0xFFFFFFFFu - (unsigned int)(s & 0xFFFFFFFFull);
      const float* cen = hd==0 ? cx : (hd==1 ? cy : (hd==2 ? cw : ch));
      v = cen[kidx & (KKC-1)];
    }
    x_sm[r][hd] = v;
    if (t >= 1 && colg == 0) out[(b*TT + t)*4 + hd] = v;
  }
  __syncthreads();
  for (int p = tid; p < 8*HH; p += 256) {
    int r = p & 7, j = p >> 3;
    float4 w = *(const float4*)&W_rb1[j*4];
    float a = b_rb1[j] + x_sm[r][0]*w.x + x_sm[r][1]*w.y + x_sm[r][2]*w.z + x_sm[r][3]*w.w;
    xr_smT[j][r] = fmaxf(a, 0.f);
  }
  int c = tid & 31, rg = tid >> 5;
  int col = c0 + c;
  float4 wsd = *(const float4*)&W_rbs[col*4];
  float acc = b_rb2[col] + b_rbs[col]
            + x_sm[rg][0]*wsd.x + x_sm[rg][1]*wsd.y
            + x_sm[rg][2]*wsd.z + x_sm[rg][3]*wsd.w;
  #pragma unroll
  for (int p = 0; p < 2; p++) {
    w_sm[0][skq[p]*4+0][swc[p]] = wReg[p].x; w_sm[0][skq[p]*4+1][swc[p]] = wReg[p].y;
    w_sm[0][skq[p]*4+2][swc[p]] = wReg[p].z; w_sm[0][skq[p]*4+3][swc[p]] = wReg[p].w;
  }
  __syncthreads();
  for (int kt = 0; kt < 8; kt++) {
    int buf = kt & 1;
    if (kt < 7) {
      int k0n = (kt+1)*64;
      #pragma unroll
      for (int p = 0; p < 2; p++)
        wReg[p] = *(const float4*)&W_rb2[(c0+swc[p])*HH + k0n + skq[p]*4];
    }
    #pragma unroll 8
    for (int kk = 0; kk < 64; kk++)
      acc = fmaf(xr_smT[kt*64+kk][rg], w_sm[buf][kk][c], acc);
    if (kt < 7) {
      __syncthreads();
      int nb = buf ^ 1;
      #pragma unroll
      for (int p = 0; p < 2; p++) {
        w_sm[nb][skq[p]*4+0][swc[p]] = wReg[p].x; w_sm[nb][skq[p]*4+1][swc[p]] = wReg[p].y;
        w_sm[nb][skq[p]*4+2][swc[p]] = wReg[p].z; w_sm[nb][skq[p]*4+3][swc[p]] = wReg[p].w;
      }
      __syncthreads();
    }
  }
  ws[OFF_XE + (r0+rg)*HH + col] = fmaxf(acc, 0.f);
}

// ---------------- batched teacher xe: grid (512, 32) ----------------
__global__ __launch_bounds__(256) void k_xe_batch(
    const float* __restrict__ obs,
    const float* __restrict__ W_rb1, const float* __restrict__ b_rb1,
    const float* __restrict__ W_rb2, const float* __restrict__ b_rb2,
    const float* __restrict__ W_rbs, const float* __restrict__ b_rbs,
    float* __restrict__ ws, float* __restrict__ out)
{
  int bid = blockIdx.x, tid = threadIdx.x, t = blockIdx.y;
  int rowg = bid >> 4, colg = bid & 15;
  int r0 = rowg*8, c0 = colg*32;
  __shared__ float x_sm[8][4];
  __shared__ float xr_smT[HH][8];
  __shared__ float w_sm[2][64][36];
  int swc[2], skq[2];
  #pragma unroll
  for (int p = 0; p < 2; p++) { int idx = tid + p*256; swc[p] = idx >> 4; skq[p] = idx & 15; }
  float4 wReg[2];
  #pragma unroll
  for (int p = 0; p < 2; p++)
    wReg[p] = *(const float4*)&W_rb2[(c0+swc[p])*HH + 0 + skq[p]*4];

  if (tid < 32) {
    int r = tid >> 2, hd = tid & 3, b = r0 + r;
    float v = obs[(b*TT + t)*4 + hd];   // teacher region only
    x_sm[r][hd] = v;
    if (t >= 1 && colg == 0) out[(b*TT + t)*4 + hd] = v;
  }
  __syncthreads();
  for (int p = tid; p < 8*HH; p += 256) {
    int r = p & 7, j = p >> 3;
    float4 w = *(const float4*)&W_rb1[j*4];
    float a = b_rb1[j] + x_sm[r][0]*w.x + x_sm[r][1]*w.y + x_sm[r][2]*w.z + x_sm[r][3]*w.w;
    xr_smT[j][r] = fmaxf(a, 0.f);
  }
  int c = tid & 31, rg = tid >> 5;
  int col = c0 + c;
  float4 wsd = *(const float4*)&W_rbs[col*4];
  float acc = b_rb2[col] + b_rbs[col]
            + x_sm[rg][0]*wsd.x + x_sm[rg][1]*wsd.y
            + x_sm[rg][2]*wsd.z + x_sm[rg][3]*wsd.w;
  #pragma unroll
  for (int p = 0; p < 2; p++) {
    w_sm[0][skq[p]*4+0][swc[p]] = wReg[p].x; w_sm[0][skq[p]*4+1][swc[p]] = wReg[p].y;
    w_sm[0][skq[p]*4+2][swc[p]] = wReg[p].z; w_sm[0][skq[p]*4+3][swc[p]] = wReg[p].w;
  }
  __syncthreads();
  for (int kt = 0; kt < 8; kt++) {
    int buf = kt & 1;
    if (kt < 7) {
      int k0n = (kt+1)*64;
      #pragma unroll
      for (int p = 0; p < 2; p++)
        wReg[p] = *(const float4*)&W_rb2[(c0+swc[p])*HH + k0n + skq[p]*4];
    }
    #pragma unroll 8
    for (int kk = 0; kk < 64; kk++)
      acc = fmaf(xr_smT[kt*64+kk][rg], w_sm[buf][kk][c], acc);
    if (kt < 7) {
      __syncthreads();
      int nb = buf ^ 1;
      #pragma unroll
      for (int p = 0; p < 2; p++) {
        w_sm[nb][skq[p]*4+0][swc[p]] = wReg[p].x; w_sm[nb][skq[p]*4+1][swc[p]] = wReg[p].y;
        w_sm[nb][skq[p]*4+2][swc[p]] = wReg[p].z; w_sm[nb][skq[p]*4+3][swc[p]] = wReg[p].w;
      }
      __syncthreads();
    }
  }
  ws[OFF_XEALL + (size_t)t*TSLOT + (r0+rg)*HH + col] = fmaxf(acc, 0.f);
}

// ---------------- AR phase 2 / batched xs ----------------
__global__ __launch_bounds__(256) void k_xs(
    const float* __restrict__ social, const float* __restrict__ W_emb,
    const float* __restrict__ b_emb, const float* __restrict__ XEp,
    float* __restrict__ outp, int t)
{
  int bid = blockIdx.x, tid = threadIdx.x;
  int rowg = bid >> 4, colg = bid & 15;
  int r0 = rowg*8, c0 = colg*32;
  __shared__ float A_smT[2][64][12];
  __shared__ float w_sm[2][64][36];
  int c = tid & 31, rg = tid >> 5;
  int col = c0 + c;
  float acc = b_emb[col];
  int swc[2], skq[2];
  #pragma unroll
  for (int p = 0; p < 2; p++) { int idx = tid + p*256; swc[p] = idx >> 4; skq[p] = idx & 15; }
  int ar = tid & 7, aq = tid >> 3;   // only tid<128 stages A
  float4 aReg, wReg[2];
  if (tid < 128) aReg = *(const float4*)&XEp[(r0+ar)*HH + 0 + aq*4];
  #pragma unroll
  for (int p = 0; p < 2; p++)
    wReg[p] = *(const float4*)&W_emb[(c0+swc[p])*768 + 0 + skq[p]*4];
  if (tid < 128) {
    A_smT[0][aq*4+0][ar] = aReg.x; A_smT[0][aq*4+1][ar] = aReg.y;
    A_smT[0][aq*4+2][ar] = aReg.z; A_smT[0][aq*4+3][ar] = aReg.w;
  }
  #pragma unroll
  for (int p = 0; p < 2; p++) {
    w_sm[0][skq[p]*4+0][swc[p]] = wReg[p].x; w_sm[0][skq[p]*4+1][swc[p]] = wReg[p].y;
    w_sm[0][skq[p]*4+2][swc[p]] = wReg[p].z; w_sm[0][skq[p]*4+3][swc[p]] = wReg[p].w;
  }
  __syncthreads();
  for (int kt = 0; kt < 12; kt++) {
    int buf = kt & 1;
    if (kt < 11) {
      int k0n = (kt+1)*64;
      if (tid < 128) {
        const float* src = (kt+1 < 8) ? &XEp[(r0+ar)*HH + k0n + aq*4]
                                      : &social[((size_t)(r0+ar)*TT + t)*SS + (k0n - HH) + aq*4];
        aReg = *(const float4*)src;
      }
      #pragma unroll
      for (int p = 0; p < 2; p++)
        wReg[p] = *(const float4*)&W_emb[(c0+swc[p])*768 + k0n + skq[p]*4];
    }
    #pragma unroll 8
    for (int kk = 0; kk < 64; kk++)
      acc = fmaf(A_smT[buf][kk][rg], w_sm[buf][kk][c], acc);
    if (kt < 11) {
      __syncthreads();
      int nb = buf ^ 1;
      if (tid < 128) {
        A_smT[nb][aq*4+0][ar] = aReg.x; A_smT[nb][aq*4+1][ar] = aReg.y;
        A_smT[nb][aq*4+2][ar] = aReg.z; A_smT[nb][aq*4+3][ar] = aReg.w;
      }
      #pragma unroll
      for (int p = 0; p < 2; p++) {
        w_sm[nb][skq[p]*4+0][swc[p]] = wReg[p].x; w_sm[nb][skq[p]*4+1][swc[p]] = wReg[p].y;
        w_sm[nb][skq[p]*4+2][swc[p]] = wReg[p].z; w_sm[nb][skq[p]*4+3][swc[p]] = wReg[p].w;
      }
      __syncthreads();
    }
  }
  outp[(r0+rg)*HH + col] = fmaxf(acc, 0.f);
}

// batched teacher xs: grid (512, 32)
__global__ __launch_bounds__(256) void k_xs_batch(
    const float* __restrict__ social, const float* __restrict__ W_emb,
    const float* __restrict__ b_emb, float* __restrict__ ws)
{
  int bid = blockIdx.x, tid = threadIdx.x, t = blockIdx.y;
  int rowg = bid >> 4, colg = bid & 15;
  int r0 = rowg*8, c0 = colg*32;
  const float* XEp = ws + OFF_XEALL + (size_t)t*TSLOT;
  float* outp = ws + OFF_XSALL + (size_t)t*TSLOT;
  __shared__ float A_smT[2][64][12];
  __shared__ float w_sm[2][64][36];
  int c = tid & 31, rg = tid >> 5;
  int col = c0 + c;
  float acc = b_emb[col];
  int swc[2], skq[2];
  #pragma unroll
  for (int p = 0; p < 2; p++) { int idx = tid + p*256; swc[p] = idx >> 4; skq[p] = idx & 15; }
  int ar = tid & 7, aq = tid >> 3;
  float4 aReg, wReg[2];
  if (tid < 128) aReg = *(const float4*)&XEp[(r0+ar)*HH + 0 + aq*4];
  #pragma unroll
  for (int p = 0; p < 2; p++)
    wReg[p] = *(const float4*)&W_emb[(c0+swc[p])*768 + 0 + skq[p]*4];
  if (tid < 128) {
    A_smT[0][aq*4+0][ar] = aReg.x; A_smT[0][aq*4+1][ar] = aReg.y;
    A_smT[0][aq*4+2][ar] = aReg.z; A_smT[0][aq*4+3][ar] = aReg.w;
  }
  #pragma unroll
  for (int p = 0; p < 2; p++) {
    w_sm[0][skq[p]*4+0][swc[p]] = wReg[p].x; w_sm[0][skq[p]*4+1][swc[p]] = wReg[p].y;
    w_sm[0][skq[p]*4+2][swc[p]] = wReg[p].z; w_sm[0][skq[p]*4+3][swc[p]] = wReg[p].w;
  }
  __syncthreads();
  for (int kt = 0; kt < 12; kt++) {
    int buf = kt & 1;
    if (kt < 11) {
      int k0n = (kt+1)*64;
      if (tid < 128) {
        const float* src = (kt+1 < 8) ? &XEp[(r0+ar)*HH + k0n + aq*4]
                                      : &social[((size_t)(r0+ar)*TT + t)*SS + (k0n - HH) + aq*4];
        aReg = *(const float4*)src;
      }
      #pragma unroll
      for (int p = 0; p < 2; p++)
        wReg[p] = *(const float4*)&W_emb[(c0+swc[p])*768 + k0n + skq[p]*4];
    }
    #pragma unroll 8
    for (int kk = 0; kk < 64; kk++)
      acc = fmaf(A_smT[buf][kk][rg], w_sm[buf][kk][c], acc);
    if (kt < 11) {
      __syncthreads();
      int nb = buf ^ 1;
      if (tid < 128) {
        A_smT[nb][aq*4+0][ar] = aReg.x; A_smT[nb][aq*4+1][ar] = aReg.y;
        A_smT[nb][aq*4+2][ar] = aReg.z; A_smT[nb][aq*4+3][ar] = aReg.w;
      }
      #pragma unroll
      for (int p = 0; p < 2; p++) {
        w_sm[nb][skq[p]*4+0][swc[p]] = wReg[p].x; w_sm[nb][skq[p]*4+1][swc[p]] = wReg[p].y;
        w_sm[nb][skq[p]*4+2][swc[p]] = wReg[p].z; w_sm[nb][skq[p]*4+3][swc[p]] = wReg[p].w;
      }
      __syncthreads();
    }
  }
  outp[(r0+rg)*HH + col] = fmaxf(acc, 0.f);
}

// ---------------- LSTM gates + cell update ----------------
__global__ __launch_bounds__(256) void k_gates(
    const float* __restrict__ W_ih, const float* __restrict__ b_ih,
    const float* __restrict__ W_hh, const float* __restrict__ b_hh,
    const float* __restrict__ XSp, const float* __restrict__ XEp,
    float* __restrict__ ws, const float* __restrict__ h_cur,
    float* __restrict__ h_nxt)
{
  int bid = blockIdx.x, tid = threadIdx.x;
  int rowg = bid >> 5, colg = bid & 31;
  int r0 = rowg*16;
  int tx = tid & 63, ty = tid >> 6;
  __shared__ float A_smT[2][64][20];
  __shared__ float w_sm[2][64][66];
  __shared__ float gt[16][66];
  int wrow = (tx & 3)*HH + colg*16 + (tx >> 2);
  float bias = b_ih[wrow] + b_hh[wrow];
  float acc[4];
  #pragma unroll
  for (int i = 0; i < 4; i++) acc[i] = bias;
  const int ar = tid & 15, aq = tid >> 4;
  int swc[4], skq[4], swr[4];
  #pragma unroll
  for (int p = 0; p < 4; p++) {
    int idx = tid + p*256;
    swc[p] = idx >> 4; skq[p] = idx & 15;
    swr[p] = (swc[p] & 3)*HH + colg*16 + (swc[p] >> 2);
  }
  float4 aReg, wReg[4];
  aReg = *(const float4*)&XSp[(r0+ar)*HH + 0 + aq*4];
  #pragma unroll
  for (int p = 0; p < 4; p++)
    wReg[p] = *(const float4*)&W_ih[swr[p]*HH + 0 + skq[p]*4];
  A_smT[0][aq*4+0][ar] = aReg.x; A_smT[0][aq*4+1][ar] = aReg.y;
  A_smT[0][aq*4+2][ar] = aReg.z; A_smT[0][aq*4+3][ar] = aReg.w;
  #pragma unroll
  for (int p = 0; p < 4; p++) {
    w_sm[0][skq[p]*4+0][swc[p]] = wReg[p].x; w_sm[0][skq[p]*4+1][swc[p]] = wReg[p].y;
    w_sm[0][skq[p]*4+2][swc[p]] = wReg[p].z; w_sm[0][skq[p]*4+3][swc[p]] = wReg[p].w;
  }
  __syncthreads();
  for (int kt = 0; kt < 16; kt++) {
    int buf = kt & 1;
    if (kt < 15) {
      int k0n = (kt+1)*64;
      const float* asrc = (kt+1 < 8) ? &XSp[(r0+ar)*HH + k0n + aq*4]
                                     : &h_cur[(r0+ar)*HH + (k0n - HH) + aq*4];
      aReg = *(const float4*)asrc;
      #pragma unroll
      for (int p = 0; p < 4; p++) {
        const float* wsrc = (kt+1 < 8) ? &W_ih[swr[p]*HH + k0n + skq[p]*4]
                                       : &W_hh[swr[p]*HH + (k0n - HH) + skq[p]*4];
        wReg[p] = *(const float4*)wsrc;
      }
    }
    #pragma unroll 4
    for (int kk = 0; kk < 64; kk++) {
      float w = w_sm[buf][kk][tx];
      float4 a = *(const float4*)&A_smT[buf][kk][ty*4];
      acc[0] = fmaf(a.x, w, acc[0]);
      acc[1] = fmaf(a.y, w, acc[1]);
      acc[2] = fmaf(a.z, w, acc[2]);
      acc[3] = fmaf(a.w, w, acc[3]);
    }
    if (kt < 15) {
      __syncthreads();
      int nb = buf ^ 1;
      A_smT[nb][aq*4+0][ar] = aReg.x; A_smT[nb][aq*4+1][ar] = aReg.y;
      A_smT[nb][aq*4+2][ar] = aReg.z; A_smT[nb][aq*4+3][ar] = aReg.w;
      #pragma unroll
      for (int p = 0; p < 4; p++) {
        w_sm[nb][skq[p]*4+0][swc[p]] = wReg[p].x; w_sm[nb][skq[p]*4+1][swc[p]] = wReg[p].y;
        w_sm[nb][skq[p]*4+2][swc[p]] = wReg[p].z; w_sm[nb][skq[p]*4+3][swc[p]] = wReg[p].w;
      }
      __syncthreads();
    }
  }
  __syncthreads();
  #pragma unroll
  for (int i = 0; i < 4; i++) gt[ty*4 + i][tx] = acc[i];
  __syncthreads();
  float* C = ws + OFF_C;
  float* XO = ws + OFF_XO;
  {
    int r = tid >> 4, jl = tid & 15;
    float4 g4 = *(const float4*)&gt[r][jl*4];   // i,f,g,o
    int b = r0 + r, jglob = colg*16 + jl;
    float co = C[b*HH + jglob];
    double si = 1.0/(1.0 + exp(-(double)g4.x));
    double sf = 1.0/(1.0 + exp(-(double)g4.y));
    double tg = tanh((double)g4.z);
    double so = 1.0/(1.0 + exp(-(double)g4.w));
    float c2 = (float)(sf*(double)co + si*tg);
    float h2 = (float)(so*tanh((double)c2));
    C[b*HH + jglob] = c2;
    h_nxt[b*HH + jglob] = h2;
    XO[b*HH + jglob] = h2 + XEp[b*HH + jglob];
  }
  if (bid == 0) {
    unsigned long long* slots = (unsigned long long*)(ws + OFF_SLOT);
    for (int p = tid; p < BB*4; p += 256) slots[p] = 0ull;
  }
}

// ---------------- in-loop heads (argmax-gated) ----------------
__global__ __launch_bounds__(256) void k_heads(
    const float* __restrict__ W_fx, const float* __restrict__ b_fx,
    const float* __restrict__ W_fy, const float* __restrict__ b_fy,
    const float* __restrict__ W_fw, const float* __restrict__ b_fw,
    const float* __restrict__ W_fh, const float* __restrict__ b_fh,
    const int* maskp, float* __restrict__ ws, float* __restrict__ out, int t)
{
  int bid = blockIdx.x, tid = threadIdx.x;
  int rowg = bid >> 6, colg = bid & 63;
  int r0 = rowg*16;
  int hd = colg >> 4;
  int kbase = (colg & 15)*64;
  int tx = tid & 63, ty = tid >> 6;
  __shared__ float A_smT[2][64][20];
  __shared__ float w_sm[2][64][66];
  const float* Wf = hd==0 ? W_fx : (hd==1 ? W_fy : (hd==2 ? W_fw : W_fh));
  const float* bf = hd==0 ? b_fx : (hd==1 ? b_fy : (hd==2 ? b_fw : b_fh));
  const float* XO = ws + OFF_XO;
  int ko = kbase + tx;
  float binit = bf[ko];
  float acc[4];
  #pragma unroll
  for (int i = 0; i < 4; i++) acc[i] = binit;
  const int ar = tid & 15, aq = tid >> 4;
  int swc[4], skq[4];
  #pragma unroll
  for (int p = 0; p < 4; p++) { int idx = tid + p*256; swc[p] = idx >> 4; skq[p] = idx & 15; }
  float4 aReg, wReg[4];
  aReg = *(const float4*)&XO[(r0+ar)*HH + 0 + aq*4];
  #pragma unroll
  for (int p = 0; p < 4; p++)
    wReg[p] = *(const float4*)&Wf[(kbase+swc[p])*HH + 0 + skq[p]*4];
  A_smT[0][aq*4+0][ar] = aReg.x; A_smT[0][aq*4+1][ar] = aReg.y;
  A_smT[0][aq*4+2][ar] = aReg.z; A_smT[0][aq*4+3][ar] = aReg.w;
  #pragma unroll
  for (int p = 0; p < 4; p++) {
    w_sm[0][skq[p]*4+0][swc[p]] = wReg[p].x; w_sm[0][skq[p]*4+1][swc[p]] = wReg[p].y;
    w_sm[0][skq[p]*4+2][swc[p]] = wReg[p].z; w_sm[0][skq[p]*4+3][swc[p]] = wReg[p].w;
  }
  __syncthreads();
  for (int kt = 0; kt < 8; kt++) {
    int buf = kt & 1;
    if (kt < 7) {
      int k0n = (kt+1)*64;
      aReg = *(const float4*)&XO[(r0+ar)*HH + k0n + aq*4];
      #pragma unroll
      for (int p = 0; p < 4; p++)
        wReg[p] = *(const float4*)&Wf[(kbase+swc[p])*HH + k0n + skq[p]*4];
    }
    #pragma unroll 4
    for (int kk = 0; kk < 64; kk++) {
      float w = w_sm[buf][kk][tx];
      float4 a = *(const float4*)&A_smT[buf][kk][ty*4];
      acc[0] = fmaf(a.x, w, acc[0]);
      acc[1] = fmaf(a.y, w, acc[1]);
      acc[2] = fmaf(a.z, w, acc[2]);
      acc[3] = fmaf(a.w, w, acc[3]);
    }
    if (kt < 7) {
      __syncthreads();
      int nb = buf ^ 1;
      A_smT[nb][aq*4+0][ar] = aReg.x; A_smT[nb][aq*4+1][ar] = aReg.y;
      A_smT[nb][aq*4+2][ar] = aReg.z; A_smT[nb][aq*4+3][ar] = aReg.w;
      #pragma unroll
      for (int p = 0; p < 4; p++) {
        w_sm[nb][skq[p]*4+0][swc[p]] = wReg[p].x; w_sm[nb][skq[p]*4+1][swc[p]] = wReg[p].y;
        w_sm[nb][skq[p]*4+2][swc[p]] = wReg[p].z; w_sm[nb][skq[p]*4+3][swc[p]] = wReg[p].w;
      }
      __syncthreads();
    }
  }
  float* obase = out + (size_t)BB*TT*4 + (size_t)hd*BB*63*KKC;
  unsigned long long* slots = (unsigned long long*)(ws + OFF_SLOT);
  bool do_argmax = (t + 1 >= decode_mask(maskp)) && (t < 62);
  #pragma unroll
  for (int i = 0; i < 4; i++) {
    int b = r0 + ty*4 + i;
    obase[(size_t)b*63*KKC + (size_t)t*KKC + ko] = acc[i];
    if (do_argmax) {
      unsigned long long cd = ((unsigned long long)encf(acc[i]) << 32)
                            | (unsigned long long)(0xFFFFFFFFu - (unsigned)ko);
      #pragma unroll
      for (int m = 1; m < 64; m <<= 1) {
        unsigned long long o = shfl_xor_u64(cd, m);
        cd = (o > cd) ? o : cd;
      }
      if (tx == 0) atomicMax(&slots[b*4 + hd], cd);
    }
  }
}

// ---------------- deferred teacher heads (r21 rework): grid (256, 31) ----------------
// 64-row x 64-col tiles, k-tile 32, double-buffered, coalesced staging, 16 acc/thread.
__global__ __launch_bounds__(256) void k_heads_def(
    const float* __restrict__ W_fx, const float* __restrict__ b_fx,
    const float* __restrict__ W_fy, const float* __restrict__ b_fy,
    const float* __restrict__ W_fw, const float* __restrict__ b_fw,
    const float* __restrict__ W_fh, const float* __restrict__ b_fh,
    const float* __restrict__ ws, float* __restrict__ out)
{
  int bid = blockIdx.x, tid = threadIdx.x, t = blockIdx.y;
  int rowg = bid >> 6, colg = bid & 63;     // 4 rowg x 64 colg
  int r0 = rowg*64;
  int hd = colg >> 4;
  int kbase = (colg & 15)*64;
  int tx = tid & 63, rg = tid >> 6;          // col ; row-group (16 rows each)
  __shared__ float A_smT[2][32][68];
  __shared__ float w_sm[2][32][68];
  const float* Wf = hd==0 ? W_fx : (hd==1 ? W_fy : (hd==2 ? W_fw : W_fh));
  const float* bf = hd==0 ? b_fx : (hd==1 ? b_fy : (hd==2 ? b_fw : b_fh));
  const float* Hn  = ws + OFF_HALL  + (size_t)(t+1)*TSLOT;
  const float* XEt = ws + OFF_XEALL + (size_t)t*TSLOT;
  int ko = kbase + tx;
  float binit = bf[ko];
  float acc[16];
  #pragma unroll
  for (int i = 0; i < 16; i++) acc[i] = binit;
  int sar[2], saq[2], swc2[2], skq2[2];
  #pragma unroll
  for (int p = 0; p < 2; p++) {
    int idx = tid + p*256;
    sar[p] = idx >> 3; saq[p] = idx & 7;
    swc2[p] = idx >> 3; skq2[p] = idx & 7;
  }
  float4 aReg[2], wReg[2];
  #pragma unroll
  for (int p = 0; p < 2; p++) {
    float4 h4 = *(const float4*)&Hn[(r0+sar[p])*HH + 0 + saq[p]*4];
    float4 e4 = *(const float4*)&XEt[(r0+sar[p])*HH + 0 + saq[p]*4];
    aReg[p] = make_float4(h4.x+e4.x, h4.y+e4.y, h4.z+e4.z, h4.w+e4.w);
    wReg[p] = *(const float4*)&Wf[(kbase+swc2[p])*HH + 0 + skq2[p]*4];
  }
  #pragma unroll
  for (int p = 0; p < 2; p++) {
    A_smT[0][saq[p]*4+0][sar[p]] = aReg[p].x; A_smT[0][saq[p]*4+1][sar[p]] = aReg[p].y;
    A_smT[0][saq[p]*4+2][sar[p]] = aReg[p].z; A_smT[0][saq[p]*4+3][sar[p]] = aReg[p].w;
    w_sm[0][skq2[p]*4+0][swc2[p]] = wReg[p].x; w_sm[0][skq2[p]*4+1][swc2[p]] = wReg[p].y;
    w_sm[0][skq2[p]*4+2][swc2[p]] = wReg[p].z; w_sm[0][skq2[p]*4+3][swc2[p]] = wReg[p].w;
  }
  __syncthreads();
  for (int kt = 0; kt < 16; kt++) {
    int buf = kt & 1;
    if (kt < 15) {
      int k0n = (kt+1)*32;
      #pragma unroll
      for (int p = 0; p < 2; p++) {
        float4 h4 = *(const float4*)&Hn[(r0+sar[p])*HH + k0n + saq[p]*4];
        float4 e4 = *(const float4*)&XEt[(r0+sar[p])*HH + k0n + saq[p]*4];
        aReg[p] = make_float4(h4.x+e4.x, h4.y+e4.y, h4.z+e4.z, h4.w+e4.w);
        wReg[p] = *(const float4*)&Wf[(kbase+swc2[p])*HH + k0n + skq2[p]*4];
      }
    }
    #pragma unroll 4
    for (int kk = 0; kk < 32; kk++) {
      float w = w_sm[buf][kk][tx];
      float4 a0 = *(const float4*)&A_smT[buf][kk][rg*16];
      float4 a1 = *(const float4*)&A_smT[buf][kk][rg*16 + 4];
      float4 a2 = *(const float4*)&A_smT[buf][kk][rg*16 + 8];
      float4 a3 = *(const float4*)&A_smT[buf][kk][rg*16 + 12];
      acc[0]  = fmaf(a0.x, w, acc[0]);  acc[1]  = fmaf(a0.y, w, acc[1]);
      acc[2]  = fmaf(a0.z, w, acc[2]);  acc[3]  = fmaf(a0.w, w, acc[3]);
      acc[4]  = fmaf(a1.x, w, acc[4]);  acc[5]  = fmaf(a1.y, w, acc[5]);
      acc[6]  = fmaf(a1.z, w, acc[6]);  acc[7]  = fmaf(a1.w, w, acc[7]);
      acc[8]  = fmaf(a2.x, w, acc[8]);  acc[9]  = fmaf(a2.y, w, acc[9]);
      acc[10] = fmaf(a2.z, w, acc[10]); acc[11] = fmaf(a2.w, w, acc[11]);
      acc[12] = fmaf(a3.x, w, acc[12]); acc[13] = fmaf(a3.y, w, acc[13]);
      acc[14] = fmaf(a3.z, w, acc[14]); acc[15] = fmaf(a3.w, w, acc[15]);
    }
    if (kt < 15) {
      __syncthreads();
      int nb = buf ^ 1;
      #pragma unroll
      for (int p = 0; p < 2; p++) {
        A_smT[nb][saq[p]*4+0][sar[p]] = aReg[p].x; A_smT[nb][saq[p]*4+1][sar[p]] = aReg[p].y;
        A_smT[nb][saq[p]*4+2][sar[p]] = aReg[p].z; A_smT[nb][saq[p]*4+3][sar[p]] = aReg[p].w;
        w_sm[nb][skq2[p]*4+0][swc2[p]] = wReg[p].x; w_sm[nb][skq2[p]*4+1][swc2[p]] = wReg[p].y;
        w_sm[nb][skq2[p]*4+2][swc2[p]] = wReg[p].z; w_sm[nb][skq2[p]*4+3][swc2[p]] = wReg[p].w;
      }
      __syncthreads();
    }
  }
  float* obase = out + (size_t)BB*TT*4 + (size_t)hd*BB*63*KKC;
  #pragma unroll
  for (int i = 0; i < 16; i++) {
    int b = r0 + rg*16 + i;
    obase[(size_t)b*63*KKC + (size_t)t*KKC + ko] = acc[i];
  }
}

extern "C" void kernel_launch(void* const* d_in, const int* in_sizes, int n_in,
                              void* d_out, int out_size, void* d_ws, size_t ws_size,
                              hipStream_t stream)
{
  const float* obs    = (const float*)d_in[0];
  const float* social = (const float*)d_in[1];
  const int*   maskp  = (const int*)d_in[2];
  const float* cx = (const float*)d_in[3];
  const float* cy = (const float*)d_in[4];
  const float* cw = (const float*)d_in[5];
  const float* ch = (const float*)d_in[6];
  const float* W_rb1 = (const float*)d_in[7];
  const float* b_rb1 = (const float*)d_in[8];
  const float* W_rb2 = (const float*)d_in[9];
  const float* b_rb2 = (const float*)d_in[10];
  const float* W_rbs = (const float*)d_in[11];
  const float* b_rbs = (const float*)d_in[12];
  const float* W_emb = (const float*)d_in[13];
  const float* b_emb = (const float*)d_in[14];
  const float* W_ih  = (const float*)d_in[15];
  const float* b_ih  = (const float*)d_in[16];
  const float* W_hh  = (const float*)d_in[17];
  const float* b_hh  = (const float*)d_in[18];
  const float* W_fx  = (const float*)d_in[19];
  const float* b_fx  = (const float*)d_in[20];
  const float* W_fy  = (const float*)d_in[21];
  const float* b_fy  = (const float*)d_in[22];
  const float* W_fw  = (const float*)d_in[23];
  const float* b_fw  = (const float*)d_in[24];
  const float* W_fh  = (const float*)d_in[25];
  const float* b_fh  = (const float*)d_in[26];
  const float* h0 = (const float*)d_in[27];
  const float* c0 = (const float*)d_in[28];
  float* ws = (float*)d_ws;
  float* out = (float*)d_out;

  const bool batched = ws_size >= (size_t)WS_NEED_FLOATS * sizeof(float);

  hipLaunchKernelGGL(k_init, dim3(512), dim3(256), 0, stream, obs, h0, c0, ws, out);

  if (batched) {
    hipLaunchKernelGGL(k_init_hall, dim3(512), dim3(256), 0, stream, h0, ws);
    hipLaunchKernelGGL(k_xe_batch, dim3(512, 32), dim3(256), 0, stream,
                       obs, W_rb1, b_rb1, W_rb2, b_rb2, W_rbs, b_rbs, ws, out);
    hipLaunchKernelGGL(k_xs_batch, dim3(512, 32), dim3(256), 0, stream,
                       social, W_emb, b_emb, ws);
    for (int t = 0; t < 32; t++) {
      const float* XSp = ws + OFF_XSALL + (size_t)t*TSLOT;
      const float* XEp = ws + OFF_XEALL + (size_t)t*TSLOT;
      const float* hc  = ws + OFF_HALL + (size_t)t*TSLOT;
      float*       hn  = ws + OFF_HALL + (size_t)(t+1)*TSLOT;
      hipLaunchKernelGGL(k_gates, dim3(512), dim3(256), 0, stream,
                         W_ih, b_ih, W_hh, b_hh, XSp, XEp, ws, hc, hn);
    }
    hipLaunchKernelGGL(k_heads, dim3(1024), dim3(256), 0, stream,
                       W_fx, b_fx, W_fy, b_fy, W_fw, b_fw, W_fh, b_fh,
                       maskp, ws, out, 31);
    for (int t = 32; t < 63; t++) {
      const float* hc = (t == 32) ? ws + OFF_HALL + (size_t)32*TSLOT
                                  : ((t & 1) ? ws + OFF_HB : ws + OFF_HA);
      float*       hn = (t & 1) ? ws + OFF_HA : ws + OFF_HB;
      if (t == 32) hn = ws + OFF_HB;
      hipLaunchKernelGGL(k_xe, dim3(512), dim3(256), 0, stream,
                         obs, cx, cy, cw, ch, maskp,
                         W_rb1, b_rb1, W_rb2, b_rb2, W_rbs, b_rbs, ws, out, t);
      hipLaunchKernelGGL(k_xs, dim3(512), dim3(256), 0, stream,
                         social, W_emb, b_emb, ws + OFF_XE, ws + OFF_XS, t);
      hipLaunchKernelGGL(k_gates, dim3(512), dim3(256), 0, stream,
                         W_ih, b_ih, W_hh, b_hh, ws + OFF_XS, ws + OFF_XE, ws, hc, hn);
      hipLaunchKernelGGL(k_heads, dim3(1024), dim3(256), 0, stream,
                         W_fx, b_fx, W_fy, b_fy, W_fw, b_fw, W_fh, b_fh,
                         maskp, ws, out, t);
    }
    hipLaunchKernelGGL(k_heads_def, dim3(256, 31), dim3(256), 0, stream,
                       W_fx, b_fx, W_fy, b_fy, W_fw, b_fw, W_fh, b_fh, ws, out);
  } else {
    for (int t = 0; t < 63; t++) {
      const float* hc = (t & 1) ? ws + OFF_HB : ws + OFF_HA;
      float*       hn = (t & 1) ? ws + OFF_HA : ws + OFF_HB;
      hipLaunchKernelGGL(k_xe, dim3(512), dim3(256), 0, stream,
                         obs, cx, cy, cw, ch, maskp,
                         W_rb1, b_rb1, W_rb2, b_rb2, W_rbs, b_rbs, ws, out, t);
      hipLaunchKernelGGL(k_xs, dim3(512), dim3(256), 0, stream,
                         social, W_emb, b_emb, ws + OFF_XE, ws + OFF_XS, t);
      hipLaunchKernelGGL(k_gates, dim3(512), dim3(256), 0, stream,
                         W_ih, b_ih, W_hh, b_hh, ws + OFF_XS, ws + OFF_XE, ws, hc, hn);
      hipLaunchKernelGGL(k_heads, dim3(1024), dim3(256), 0, stream,
                         W_fx, b_fx, W_fy, b_fy, W_fw, b_fw, W_fh, b_fh,
                         maskp, ws, out, t);
    }
  }
}